// Round 1
// baseline (8004.694 us; speedup 1.0000x reference)
//
#include <hip/hip_runtime.h>
#include <math.h>

#define Bz 8
#define Sz 1024
#define INz 128
#define Ez 512
#define Hz 8
#define HDz 64
#define FFz 2048
#define Lz 4
#define Nz (Bz*Sz)   // 8192
#define EPSf 1e-5f

// ---------------- generic tiled GEMM: C[M,Nc] = A[M,K] @ W[Nc,K]^T + bias, optional relu
__global__ __launch_bounds__(256) void gemm_nt(const float* __restrict__ A,
    const float* __restrict__ W, const float* __restrict__ bias,
    float* __restrict__ C, int M, int Nc, int K, int lda, int ldc, int relu)
{
  __shared__ float As[16][68];
  __shared__ float Ws[16][68];
  int tx = threadIdx.x & 15, ty = threadIdx.x >> 4;
  int bm = blockIdx.y * 64, bn = blockIdx.x * 64;
  float acc[4][4] = {};
  for (int k0 = 0; k0 < K; k0 += 16) {
    #pragma unroll
    for (int i = 0; i < 4; ++i) {
      int r = (i << 4) + ty;
      As[tx][r] = A[(size_t)(bm + r) * lda + k0 + tx];
      Ws[tx][r] = W[(size_t)(bn + r) * K + k0 + tx];
    }
    __syncthreads();
    #pragma unroll
    for (int kk = 0; kk < 16; ++kk) {
      float a[4], b[4];
      #pragma unroll
      for (int i = 0; i < 4; ++i) a[i] = As[kk][(ty << 2) + i];
      #pragma unroll
      for (int j = 0; j < 4; ++j) b[j] = Ws[kk][(tx << 2) + j];
      #pragma unroll
      for (int i = 0; i < 4; ++i)
        #pragma unroll
        for (int j = 0; j < 4; ++j) acc[i][j] += a[i] * b[j];
    }
    __syncthreads();
  }
  #pragma unroll
  for (int i = 0; i < 4; ++i) {
    int row = bm + (ty << 2) + i;
    #pragma unroll
    for (int j = 0; j < 4; ++j) {
      int col = bn + (tx << 2) + j;
      float v = acc[i][j] + bias[col];
      if (relu) v = fmaxf(v, 0.f);
      C[(size_t)row * ldc + col] = v;
    }
  }
}

// ---------------- BatchNorm stats over N rows, per channel (E channels)
__global__ __launch_bounds__(256) void bn_stats(const float* __restrict__ x, float* __restrict__ st)
{
  int c = blockIdx.x;
  float s = 0.f, q = 0.f;
  for (int r = threadIdx.x; r < Nz; r += 256) {
    float v = x[(size_t)r * Ez + c];
    s += v; q += v * v;
  }
  for (int o = 32; o; o >>= 1) { s += __shfl_down(s, o); q += __shfl_down(q, o); }
  __shared__ float shs[4], shq[4];
  int w = threadIdx.x >> 6;
  if ((threadIdx.x & 63) == 0) { shs[w] = s; shq[w] = q; }
  __syncthreads();
  if (threadIdx.x == 0) {
    s = shs[0] + shs[1] + shs[2] + shs[3];
    q = shq[0] + shq[1] + shq[2] + shq[3];
    float mu = s / (float)Nz;
    float var = q / (float)Nz - mu * mu;
    st[c] = mu;
    st[Ez + c] = rsqrtf(var + EPSf);
  }
}

// ---------------- BN apply + positional encoding
__global__ __launch_bounds__(256) void bn_apply_pe(const float* __restrict__ x0,
    const float* __restrict__ st, const float* __restrict__ g,
    const float* __restrict__ b, float* __restrict__ x)
{
  int idx = blockIdx.x * 256 + threadIdx.x;  // over N*E (grid exact)
  int c = idx & (Ez - 1);
  int r = idx >> 9;
  int s = r & (Sz - 1);
  float dt = expf((float)(c & ~1) * (-9.210340371976184f / (float)Ez));
  float ang = (float)s * dt;
  float pe = (c & 1) ? cosf(ang) : sinf(ang);
  float mu = st[c], rs = st[Ez + c];
  x[idx] = (x0[idx] - mu) * rs * g[c] + b[c] + pe;
}

// ---------------- distance bias: db = exp(scale * (1 - d/rowmax(d)))
__global__ __launch_bounds__(256) void dist_bias_k(const float* __restrict__ dist,
    const float* __restrict__ dsc, float* __restrict__ db)
{
  size_t base = (size_t)blockIdx.x * Sz;
  float m = -1e30f;
  for (int j = threadIdx.x; j < Sz; j += 256) m = fmaxf(m, dist[base + j]);
  for (int o = 32; o; o >>= 1) m = fmaxf(m, __shfl_down(m, o));
  __shared__ float sh[4];
  if ((threadIdx.x & 63) == 0) sh[threadIdx.x >> 6] = m;
  __syncthreads();
  m = fmaxf(fmaxf(sh[0], sh[1]), fmaxf(sh[2], sh[3]));
  float sc = dsc[0];
  float inv = 1.f / m;
  for (int j = threadIdx.x; j < Sz; j += 256)
    db[base + j] = expf(sc * (1.f - dist[base + j] * inv));
}

// ---------------- attention pass 1: per (b,h,q) softmax max m and sum Z
// qk layout: [N,1024], cols 0..511 = q (head h at h*64), cols 512..1023 = k
__global__ __launch_bounds__(256) void attn_stats(const float* __restrict__ qk,
    float* __restrict__ stats)
{
  int qt = blockIdx.x & 63;
  int h  = (blockIdx.x >> 6) & 7;
  int b  = blockIdx.x >> 9;
  int q0 = qt << 4;
  __shared__ float Qs[16][68];
  __shared__ float Ks[64][68];
  __shared__ float red[16][17];
  __shared__ float m_s[16], z_s[16], nm[16];
  int tid = threadIdx.x;
  #pragma unroll
  for (int i = 0; i < 4; ++i) {
    int e = i * 256 + tid;
    int qr = e >> 6, d = e & 63;
    Qs[qr][d] = qk[(size_t)(b * Sz + q0 + qr) * 1024 + h * 64 + d];
  }
  if (tid < 16) { m_s[tid] = -1e30f; z_s[tid] = 0.f; }
  __syncthreads();
  int q_l = tid & 15, kg = tid >> 4;
  for (int kt = 0; kt < Sz; kt += 64) {
    #pragma unroll
    for (int i = 0; i < 16; ++i) {
      int e = i * 256 + tid;
      int kr = e >> 6, d = e & 63;
      Ks[kr][d] = qk[(size_t)(b * Sz + kt + kr) * 1024 + 512 + h * 64 + d];
    }
    __syncthreads();
    float sc[4];
    #pragma unroll
    for (int j = 0; j < 4; ++j) {
      int kk = (kg << 2) + j;
      const float4* qv = (const float4*)&Qs[q_l][0];
      const float4* kv = (const float4*)&Ks[kk][0];
      float dot = 0.f;
      #pragma unroll
      for (int d4 = 0; d4 < 16; ++d4) {
        float4 a = qv[d4], c = kv[d4];
        dot += a.x * c.x + a.y * c.y + a.z * c.z + a.w * c.w;
      }
      sc[j] = dot * 0.125f;
    }
    float lm = fmaxf(fmaxf(sc[0], sc[1]), fmaxf(sc[2], sc[3]));
    red[q_l][kg] = lm;
    __syncthreads();
    if (kg == 0) {
      float tm = red[q_l][0];
      #pragma unroll
      for (int i = 1; i < 16; ++i) tm = fmaxf(tm, red[q_l][i]);
      nm[q_l] = fmaxf(m_s[q_l], tm);
    }
    __syncthreads();
    float nmv = nm[q_l];
    float zp = __expf(sc[0] - nmv) + __expf(sc[1] - nmv)
             + __expf(sc[2] - nmv) + __expf(sc[3] - nmv);
    red[q_l][kg] = zp;
    __syncthreads();
    if (kg == 0) {
      float zt = 0.f;
      #pragma unroll
      for (int i = 0; i < 16; ++i) zt += red[q_l][i];
      z_s[q_l] = z_s[q_l] * __expf(m_s[q_l] - nmv) + zt;
      m_s[q_l] = nmv;
    }
    __syncthreads();
  }
  if (tid < 16) {
    size_t o = ((size_t)(b * Hz + h) * Sz + q0 + tid) * 2;
    stats[o] = m_s[tid];
    stats[o + 1] = z_s[tid];
  }
}

// ---------------- attention pass 2: out[b,q,:] = sum_k p*x[b,k,:] / sum_k p
// p = (1/H * sum_h exp(s_h - m_h)/Z_h) * dist_bias
__global__ __launch_bounds__(256) void attn_apply(const float* __restrict__ qk,
    const float* __restrict__ x, const float* __restrict__ db,
    const float* __restrict__ stats, float* __restrict__ out)
{
  int qt = blockIdx.x & 63;
  int b  = blockIdx.x >> 6;
  int q0 = qt << 4;
  __shared__ float Qs[16][516];
  __shared__ float Ks[16][516];
  __shared__ float XsT[512][20];
  __shared__ float Ps[16][17];
  __shared__ float mh[16][8], zi[16][8];
  __shared__ float den[16];
  int tid = threadIdx.x;
  #pragma unroll
  for (int i = 0; i < 32; ++i) {
    int e = i * 256 + tid;
    int qr = e >> 9, c = e & 511;
    Qs[qr][c] = qk[(size_t)(b * Sz + q0 + qr) * 1024 + c];
  }
  if (tid < 128) {
    int ql = tid >> 3, h = tid & 7;
    size_t o = ((size_t)(b * Hz + h) * Sz + q0 + ql) * 2;
    mh[ql][h] = stats[o];
    zi[ql][h] = 1.f / stats[o + 1];
  }
  if (tid < 16) den[tid] = 0.f;
  float acc[32];
  #pragma unroll
  for (int j = 0; j < 32; ++j) acc[j] = 0.f;
  int q_l = tid >> 4, cg = tid & 15;
  __syncthreads();
  for (int kt = 0; kt < Sz; kt += 16) {
    #pragma unroll
    for (int i = 0; i < 32; ++i) {
      int e = i * 256 + tid;
      int kr = e >> 9, c = e & 511;
      Ks[kr][c] = qk[(size_t)(b * Sz + kt + kr) * 1024 + 512 + c];
      XsT[c][kr] = x[(size_t)(b * Sz + kt + kr) * 512 + c];
    }
    __syncthreads();
    float p = 0.f;
    #pragma unroll
    for (int h = 0; h < 8; ++h) {
      const float4* qv = (const float4*)&Qs[q_l][h * 64];
      const float4* kv = (const float4*)&Ks[cg][h * 64];
      float dot = 0.f;
      #pragma unroll
      for (int d4 = 0; d4 < 16; ++d4) {
        float4 a = qv[d4], c2 = kv[d4];
        dot += a.x * c2.x + a.y * c2.y + a.z * c2.z + a.w * c2.w;
      }
      p += __expf(dot * 0.125f - mh[q_l][h]) * zi[q_l][h];
    }
    p *= 0.125f;  // 1/H
    p *= db[(size_t)(b * Sz + q0 + q_l) * Sz + kt + cg];
    Ps[q_l][cg] = p;
    __syncthreads();
    if (cg == 0) {
      float sden = 0.f;
      #pragma unroll
      for (int i = 0; i < 16; ++i) sden += Ps[q_l][i];
      den[q_l] += sden;
    }
    float pv[16];
    #pragma unroll
    for (int k = 0; k < 16; ++k) pv[k] = Ps[q_l][k];
    #pragma unroll
    for (int j = 0; j < 32; ++j) {
      const float4* xp = (const float4*)&XsT[cg + (j << 4)][0];
      float4 x0 = xp[0], x1 = xp[1], x2 = xp[2], x3 = xp[3];
      acc[j] += pv[0]*x0.x + pv[1]*x0.y + pv[2]*x0.z + pv[3]*x0.w
              + pv[4]*x1.x + pv[5]*x1.y + pv[6]*x1.z + pv[7]*x1.w
              + pv[8]*x2.x + pv[9]*x2.y + pv[10]*x2.z + pv[11]*x2.w
              + pv[12]*x3.x + pv[13]*x3.y + pv[14]*x3.z + pv[15]*x3.w;
    }
    __syncthreads();
  }
  float rd = 1.f / den[q_l];
  size_t ob = (size_t)(b * Sz + q0 + q_l) * 512;
  #pragma unroll
  for (int j = 0; j < 32; ++j) out[ob + cg + (j << 4)] = acc[j] * rd;
}

// ---------------- residual add + LayerNorm (row-wise, E=512), in-place safe
__global__ __launch_bounds__(256) void add_ln(const float* __restrict__ xin,
    const float* __restrict__ dly, const float* __restrict__ g,
    const float* __restrict__ bb, float* __restrict__ xout)
{
  size_t base = (size_t)blockIdx.x * Ez;
  int t = threadIdx.x;
  float a0 = xin[base + t] + dly[base + t];
  float a1 = xin[base + t + 256] + dly[base + t + 256];
  float s = a0 + a1, q = a0 * a0 + a1 * a1;
  for (int o = 32; o; o >>= 1) { s += __shfl_down(s, o); q += __shfl_down(q, o); }
  __shared__ float shs[4], shq[4];
  if ((t & 63) == 0) { shs[t >> 6] = s; shq[t >> 6] = q; }
  __syncthreads();
  s = shs[0] + shs[1] + shs[2] + shs[3];
  q = shq[0] + shq[1] + shq[2] + shq[3];
  float mu = s * (1.f / Ez);
  float var = q * (1.f / Ez) - mu * mu;
  float rs = rsqrtf(var + EPSf);
  xout[base + t] = (a0 - mu) * rs * g[t] + bb[t];
  xout[base + t + 256] = (a1 - mu) * rs * g[t + 256] + bb[t + 256];
}

extern "C" void kernel_launch(void* const* d_in, const int* in_sizes, int n_in,
                              void* d_out, int out_size, void* d_ws, size_t ws_size,
                              hipStream_t stream)
{
  const float* src        = (const float*)d_in[0];
  const float* distances  = (const float*)d_in[1];
  const float* proj_w     = (const float*)d_in[2];
  const float* proj_b     = (const float*)d_in[3];
  const float* bn_g       = (const float*)d_in[4];
  const float* bn_b       = (const float*)d_in[5];
  const float* in_proj_w  = (const float*)d_in[6];
  const float* in_proj_b  = (const float*)d_in[7];
  const float* dist_scale = (const float*)d_in[8];
  const float* lin1_w     = (const float*)d_in[9];
  const float* lin1_b     = (const float*)d_in[10];
  const float* lin2_w     = (const float*)d_in[11];
  const float* lin2_b     = (const float*)d_in[12];
  const float* n1_g       = (const float*)d_in[13];
  const float* n1_b       = (const float*)d_in[14];
  const float* n2_g       = (const float*)d_in[15];
  const float* n2_b       = (const float*)d_in[16];

  float* x = (float*)d_out;                         // activations [N,E] live in d_out
  float* ws    = (float*)d_ws;
  float* db    = ws;                                // B*S*S       = 8388608
  float* stats = db + (size_t)Bz * Sz * Sz;         // B*H*S*2     = 131072
  float* bnst  = stats + (size_t)Bz * Hz * Sz * 2;  // 2*E
  float* aout  = bnst + 2 * Ez;                     // N*E         = 4194304
  float* big   = aout + (size_t)Nz * Ez;            // N*FF        = 16777216 (qk or ff1)
  float* x0    = aout;                              // temp for pre-BN activations

  // input projection: x0 = src @ proj_w^T + proj_b
  gemm_nt<<<dim3(Ez / 64, Nz / 64), 256, 0, stream>>>(src, proj_w, proj_b, x0,
      Nz, Ez, INz, INz, Ez, 0);
  // batch-norm (training-mode batch stats) + positional encoding -> x
  bn_stats<<<Ez, 256, 0, stream>>>(x0, bnst);
  bn_apply_pe<<<(Nz * Ez) / 256, 256, 0, stream>>>(x0, bnst, bn_g, bn_b, x);
  // distance bias (shared by all layers)
  dist_bias_k<<<Bz * Sz, 256, 0, stream>>>(distances, dist_scale, db);

  for (int l = 0; l < Lz; ++l) {
    // q,k projection only (v is unused by the reference math): [N,1024]
    gemm_nt<<<dim3(1024 / 64, Nz / 64), 256, 0, stream>>>(x, in_proj_w, in_proj_b,
        big, Nz, 1024, Ez, Ez, 1024, 0);
    attn_stats<<<Bz * Hz * (Sz / 16), 256, 0, stream>>>(big, stats);
    attn_apply<<<Bz * (Sz / 16), 256, 0, stream>>>(big, x, db, stats, aout);
    add_ln<<<Nz, 256, 0, stream>>>(x, aout, n1_g, n1_b, x);
    // FF
    gemm_nt<<<dim3(FFz / 64, Nz / 64), 256, 0, stream>>>(x, lin1_w, lin1_b,
        big, Nz, FFz, Ez, Ez, FFz, 1);
    gemm_nt<<<dim3(Ez / 64, Nz / 64), 256, 0, stream>>>(big, lin2_w, lin2_b,
        aout, Nz, Ez, FFz, FFz, Ez, 0);
    add_ln<<<Nz, 256, 0, stream>>>(x, aout, n2_g, n2_b, x);
  }
}

// Round 2
// 1282.901 us; speedup vs baseline: 6.2395x; 6.2395x over previous
//
#include <hip/hip_runtime.h>
#include <hip/hip_bf16.h>
#include <math.h>

#define Bz 8
#define Sz 1024
#define INz 128
#define Ez 512
#define Hz 8
#define HDz 64
#define FFz 2048
#define Lz 4
#define Nz (Bz*Sz)   // 8192
#define EPSf 1e-5f

typedef __attribute__((ext_vector_type(8))) short short8;
typedef __attribute__((ext_vector_type(4))) float floatx4;
#define MFMA16(a,b,c) __builtin_amdgcn_mfma_f32_16x16x32_bf16(a,b,c,0,0,0)

typedef __hip_bfloat16 bf16;

__device__ inline float b2f(bf16 v) { return __bfloat162float(v); }
__device__ inline bf16 f2b(float v) { return __float2bfloat16(v); }

// ---------------- fp32 -> bf16 cast
__global__ __launch_bounds__(256) void cast_f2b(const float* __restrict__ in,
    bf16* __restrict__ out, int n)
{
  int i = blockIdx.x * 256 + threadIdx.x;
  if (i < n) out[i] = f2b(in[i]);
}

// ---------------- unified bf16 MFMA NT GEMM
// C[M,N] = A[M,K] @ Wm[N,K]^T (+bias) (relu?) (*1/rowscale[row]?)
// batched via blockIdx.z with element strides sA,sW,sC. lda=K, ldw=K, ldc=N.
__global__ __launch_bounds__(256) void gemm_bt(
    const bf16* __restrict__ A, const bf16* __restrict__ Wm,
    const float* __restrict__ bias, float* __restrict__ Cf,
    bf16* __restrict__ Cb, const float* __restrict__ rowscale,
    int M, int N, int K, long sA, long sW, long sC, int relu)
{
  int z = blockIdx.z;
  A  += (size_t)z * sA;
  Wm += (size_t)z * sW;
  if (rowscale) rowscale += (size_t)z * M;
  size_t cbase = (size_t)z * sC;
  int bm = blockIdx.y * 128, bn = blockIdx.x * 128;
  __shared__ bf16 As[128][72];   // 64 + 8 pad; row stride 144B (16B mult, 2-way banks)
  __shared__ bf16 Bs[128][72];
  int t = threadIdx.x, wave = t >> 6, lane = t & 63;
  int wm = (wave >> 1) * 64, wn = (wave & 1) * 64;
  int fr = lane & 15, fo = (lane >> 4) * 8;
  floatx4 acc[4][4];
  #pragma unroll
  for (int i = 0; i < 4; ++i)
    #pragma unroll
    for (int j = 0; j < 4; ++j) acc[i][j] = (floatx4){0.f, 0.f, 0.f, 0.f};

  for (int k0 = 0; k0 < K; k0 += 64) {
    #pragma unroll
    for (int i = 0; i < 4; ++i) {
      int idx = i * 256 + t, row = idx >> 3, c4 = idx & 7;
      *(float4*)&As[row][c4 * 8] = *(const float4*)(A  + (size_t)(bm + row) * K + k0 + c4 * 8);
      *(float4*)&Bs[row][c4 * 8] = *(const float4*)(Wm + (size_t)(bn + row) * K + k0 + c4 * 8);
    }
    __syncthreads();
    #pragma unroll
    for (int ks = 0; ks < 2; ++ks) {
      short8 af[4], bfv[4];
      #pragma unroll
      for (int rt = 0; rt < 4; ++rt) af[rt]  = *(const short8*)&As[wm + rt * 16 + fr][ks * 32 + fo];
      #pragma unroll
      for (int ct = 0; ct < 4; ++ct) bfv[ct] = *(const short8*)&Bs[wn + ct * 16 + fr][ks * 32 + fo];
      #pragma unroll
      for (int rt = 0; rt < 4; ++rt)
        #pragma unroll
        for (int ct = 0; ct < 4; ++ct)
          acc[rt][ct] = MFMA16(af[rt], bfv[ct], acc[rt][ct]);
    }
    __syncthreads();
  }
  // epilogue: C layout col=lane&15, row=(lane>>4)*4+reg
  #pragma unroll
  for (int rt = 0; rt < 4; ++rt) {
    #pragma unroll
    for (int r = 0; r < 4; ++r) {
      int row = bm + wm + rt * 16 + (lane >> 4) * 4 + r;
      float rs = rowscale ? (1.f / rowscale[row]) : 1.f;
      #pragma unroll
      for (int ct = 0; ct < 4; ++ct) {
        int col = bn + wn + ct * 16 + fr;
        float v = acc[rt][ct][r] + (bias ? bias[col] : 0.f);
        if (relu) v = fmaxf(v, 0.f);
        v *= rs;
        if (Cf) Cf[cbase + (size_t)row * N + col] = v;
        if (Cb) Cb[cbase + (size_t)row * N + col] = f2b(v);
      }
    }
  }
}

// ---------------- BatchNorm stats over N rows, per channel
__global__ __launch_bounds__(256) void bn_stats(const float* __restrict__ x, float* __restrict__ st)
{
  int c = blockIdx.x;
  float s = 0.f, q = 0.f;
  for (int r = threadIdx.x; r < Nz; r += 256) {
    float v = x[(size_t)r * Ez + c];
    s += v; q += v * v;
  }
  for (int o = 32; o; o >>= 1) { s += __shfl_down(s, o); q += __shfl_down(q, o); }
  __shared__ float shs[4], shq[4];
  int w = threadIdx.x >> 6;
  if ((threadIdx.x & 63) == 0) { shs[w] = s; shq[w] = q; }
  __syncthreads();
  if (threadIdx.x == 0) {
    s = shs[0] + shs[1] + shs[2] + shs[3];
    q = shq[0] + shq[1] + shq[2] + shq[3];
    float mu = s / (float)Nz;
    float var = q / (float)Nz - mu * mu;
    st[c] = mu;
    st[Ez + c] = rsqrtf(var + EPSf);
  }
}

// ---------------- BN apply + positional encoding -> x fp32 and xb bf16
__global__ __launch_bounds__(256) void bn_apply_pe(const float* __restrict__ x0,
    const float* __restrict__ st, const float* __restrict__ g,
    const float* __restrict__ b, float* __restrict__ x, bf16* __restrict__ xb)
{
  int idx = blockIdx.x * 256 + threadIdx.x;
  int c = idx & (Ez - 1);
  int r = idx >> 9;
  int s = r & (Sz - 1);
  float dt = expf((float)(c & ~1) * (-9.210340371976184f / (float)Ez));
  float ang = (float)s * dt;
  float pe = (c & 1) ? cosf(ang) : sinf(ang);
  float mu = st[c], rs = st[Ez + c];
  float v = (x0[idx] - mu) * rs * g[c] + b[c] + pe;
  x[idx] = v;
  xb[idx] = f2b(v);
}

// ---------------- distance bias -> bf16
__global__ __launch_bounds__(256) void dist_bias_k(const float* __restrict__ dist,
    const float* __restrict__ dsc, bf16* __restrict__ db)
{
  size_t base = (size_t)blockIdx.x * Sz;
  float m = -1e30f;
  for (int j = threadIdx.x; j < Sz; j += 256) m = fmaxf(m, dist[base + j]);
  for (int o = 32; o; o >>= 1) m = fmaxf(m, __shfl_down(m, o));
  __shared__ float sh[4];
  if ((threadIdx.x & 63) == 0) sh[threadIdx.x >> 6] = m;
  __syncthreads();
  m = fmaxf(fmaxf(sh[0], sh[1]), fmaxf(sh[2], sh[3]));
  float sc = dsc[0];
  float inv = 1.f / m;
  for (int j = threadIdx.x; j < Sz; j += 256)
    db[base + j] = f2b(expf(sc * (1.f - dist[base + j] * inv)));
}

// ---------------- transpose xb [B*S,E] -> xT [B][E][S]
__global__ __launch_bounds__(256) void transpose_xb(const bf16* __restrict__ xb,
    bf16* __restrict__ xT)
{
  int b = blockIdx.z, e0 = blockIdx.y * 32, s0 = blockIdx.x * 32;
  __shared__ bf16 T[32][40];
  int t = threadIdx.x, row = t >> 3, c = t & 7;
  *(ushort4*)&T[row][c * 4] = *(const ushort4*)(xb + (size_t)(b * Sz + s0 + row) * Ez + e0 + c * 4);
  __syncthreads();
  ushort4 v;
  unsigned short* vp = (unsigned short*)&v;
  #pragma unroll
  for (int i = 0; i < 4; ++i) vp[i] = *(const unsigned short*)&T[c * 4 + i][row];
  *(ushort4*)(xT + ((size_t)b * Ez + e0 + row) * Sz + s0 + c * 4) = v;
}

// ---------------- MFMA attention stats: per (b,h,q) running max m and sum Z
// qk [N,1024] bf16: cols 0..511 = q, 512..1023 = k (head h at h*64)
__global__ __launch_bounds__(256) void attn_stats2(const bf16* __restrict__ qk,
    float* __restrict__ stats)
{
  int qt = blockIdx.x, h = blockIdx.y, b = blockIdx.z;
  int q0 = qt * 64;
  __shared__ bf16 Qs[64][72];
  __shared__ bf16 Ks[128][72];
  int t = threadIdx.x, wave = t >> 6, lane = t & 63;
  int fr = lane & 15, fo = (lane >> 4) * 8;
  #pragma unroll
  for (int i = 0; i < 2; ++i) {
    int idx = i * 256 + t, row = idx >> 3, c4 = idx & 7;
    *(float4*)&Qs[row][c4 * 8] =
      *(const float4*)(qk + (size_t)(b * Sz + q0 + row) * 1024 + h * 64 + c4 * 8);
  }
  __syncthreads();
  short8 aq0 = *(const short8*)&Qs[wave * 16 + fr][fo];
  short8 aq1 = *(const short8*)&Qs[wave * 16 + fr][32 + fo];
  float m_run[4] = {-1e30f, -1e30f, -1e30f, -1e30f};
  float z_run[4] = {0.f, 0.f, 0.f, 0.f};
  for (int k0 = 0; k0 < Sz; k0 += 128) {
    __syncthreads();
    #pragma unroll
    for (int i = 0; i < 4; ++i) {
      int idx = i * 256 + t, row = idx >> 3, c4 = idx & 7;
      *(float4*)&Ks[row][c4 * 8] =
        *(const float4*)(qk + (size_t)(b * Sz + k0 + row) * 1024 + 512 + h * 64 + c4 * 8);
    }
    __syncthreads();
    float sc[8][4];
    #pragma unroll
    for (int j = 0; j < 8; ++j) {
      floatx4 a4 = (floatx4){0.f, 0.f, 0.f, 0.f};
      short8 b0 = *(const short8*)&Ks[j * 16 + fr][fo];
      short8 b1 = *(const short8*)&Ks[j * 16 + fr][32 + fo];
      a4 = MFMA16(aq0, b0, a4);
      a4 = MFMA16(aq1, b1, a4);
      #pragma unroll
      for (int r = 0; r < 4; ++r) sc[j][r] = a4[r] * 0.125f;
    }
    #pragma unroll
    for (int r = 0; r < 4; ++r) {
      float vm = sc[0][r];
      #pragma unroll
      for (int j = 1; j < 8; ++j) vm = fmaxf(vm, sc[j][r]);
      #pragma unroll
      for (int o = 1; o < 16; o <<= 1) vm = fmaxf(vm, __shfl_xor(vm, o, 16));
      float mn = fmaxf(m_run[r], vm);
      float zb = 0.f;
      #pragma unroll
      for (int j = 0; j < 8; ++j) zb += __expf(sc[j][r] - mn);
      #pragma unroll
      for (int o = 1; o < 16; o <<= 1) zb += __shfl_xor(zb, o, 16);
      z_run[r] = z_run[r] * __expf(m_run[r] - mn) + zb;
      m_run[r] = mn;
    }
  }
  if (fr == 0) {
    int qb = q0 + wave * 16 + (lane >> 4) * 4;
    #pragma unroll
    for (int r = 0; r < 4; ++r) {
      size_t o = ((size_t)(b * Hz + h) * Sz + qb + r) * 2;
      stats[o] = m_run[r];
      stats[o + 1] = z_run[r];
    }
  }
}

// ---------------- MFMA scores: aw[b,q,k] = (1/H * sum_h softmax_h) * db  (bf16)
__global__ __launch_bounds__(256) void scores_bias(const bf16* __restrict__ qk,
    const bf16* __restrict__ db, const float* __restrict__ stats,
    bf16* __restrict__ aw)
{
  int kt = blockIdx.x, qt = blockIdx.y, b = blockIdx.z;
  int q0 = qt * 32, k0 = kt * 32;
  __shared__ bf16 Qs[32][520];
  __shared__ bf16 Ks[32][520];
  __shared__ float mS[32][8], ziS[32][8];
  int t = threadIdx.x, wave = t >> 6, lane = t & 63;
  int fr = lane & 15, fo = (lane >> 4) * 8;
  #pragma unroll
  for (int i = 0; i < 8; ++i) {
    int idx = i * 256 + t, row = idx >> 6, c4 = idx & 63;
    *(float4*)&Qs[row][c4 * 8] = *(const float4*)(qk + (size_t)(b * Sz + q0 + row) * 1024 + c4 * 8);
    *(float4*)&Ks[row][c4 * 8] = *(const float4*)(qk + (size_t)(b * Sz + k0 + row) * 1024 + 512 + c4 * 8);
  }
  {
    int q = t >> 3, h = t & 7;
    size_t o = ((size_t)(b * Hz + h) * Sz + q0 + q) * 2;
    mS[q][h] = stats[o];
    ziS[q][h] = 1.f / stats[o + 1];
  }
  __syncthreads();
  int wq = (wave >> 1) * 16, wk = (wave & 1) * 16;
  floatx4 acch[8];
  #pragma unroll
  for (int h = 0; h < 8; ++h) {
    acch[h] = (floatx4){0.f, 0.f, 0.f, 0.f};
    #pragma unroll
    for (int ks = 0; ks < 2; ++ks) {
      short8 a = *(const short8*)&Qs[wq + fr][h * 64 + ks * 32 + fo];
      short8 bb = *(const short8*)&Ks[wk + fr][h * 64 + ks * 32 + fo];
      acch[h] = MFMA16(a, bb, acch[h]);
    }
  }
  #pragma unroll
  for (int r = 0; r < 4; ++r) {
    int qloc = wq + (lane >> 4) * 4 + r;
    int kloc = wk + fr;
    float p = 0.f;
    #pragma unroll
    for (int h = 0; h < 8; ++h)
      p += __expf(acch[h][r] * 0.125f - mS[qloc][h]) * ziS[qloc][h];
    size_t off = (size_t)(b * Sz + q0 + qloc) * Sz + k0 + kloc;
    p *= 0.125f * b2f(db[off]);
    aw[off] = f2b(p);
  }
}

// ---------------- row sums of aw -> den
__global__ __launch_bounds__(256) void rowsum(const bf16* __restrict__ aw,
    float* __restrict__ den)
{
  size_t base = (size_t)blockIdx.x * Sz;
  int t = threadIdx.x;
  ushort4 u = *(const ushort4*)(aw + base + t * 4);
  float s = __uint_as_float((unsigned)u.x << 16) + __uint_as_float((unsigned)u.y << 16)
          + __uint_as_float((unsigned)u.z << 16) + __uint_as_float((unsigned)u.w << 16);
  for (int o = 32; o; o >>= 1) s += __shfl_down(s, o);
  __shared__ float sh[4];
  if ((t & 63) == 0) sh[t >> 6] = s;
  __syncthreads();
  if (t == 0) den[blockIdx.x] = sh[0] + sh[1] + sh[2] + sh[3];
}

// ---------------- residual add + LayerNorm -> x fp32, xb bf16
__global__ __launch_bounds__(256) void add_ln(const float* __restrict__ xin,
    const float* __restrict__ dly, const float* __restrict__ g,
    const float* __restrict__ bb, float* __restrict__ xout, bf16* __restrict__ xbout)
{
  size_t base = (size_t)blockIdx.x * Ez;
  int t = threadIdx.x;
  float a0 = xin[base + t] + dly[base + t];
  float a1 = xin[base + t + 256] + dly[base + t + 256];
  float s = a0 + a1, q = a0 * a0 + a1 * a1;
  for (int o = 32; o; o >>= 1) { s += __shfl_down(s, o); q += __shfl_down(q, o); }
  __shared__ float shs[4], shq[4];
  if ((t & 63) == 0) { shs[t >> 6] = s; shq[t >> 6] = q; }
  __syncthreads();
  s = shs[0] + shs[1] + shs[2] + shs[3];
  q = shq[0] + shq[1] + shq[2] + shq[3];
  float mu = s * (1.f / Ez);
  float var = q * (1.f / Ez) - mu * mu;
  float rs = rsqrtf(var + EPSf);
  float v0 = (a0 - mu) * rs * g[t] + bb[t];
  float v1 = (a1 - mu) * rs * g[t + 256] + bb[t + 256];
  xout[base + t] = v0;
  xout[base + t + 256] = v1;
  xbout[base + t] = f2b(v0);
  xbout[base + t + 256] = f2b(v1);
}

extern "C" void kernel_launch(void* const* d_in, const int* in_sizes, int n_in,
                              void* d_out, int out_size, void* d_ws, size_t ws_size,
                              hipStream_t stream)
{
  const float* src        = (const float*)d_in[0];
  const float* distances  = (const float*)d_in[1];
  const float* proj_w     = (const float*)d_in[2];
  const float* proj_b     = (const float*)d_in[3];
  const float* bn_g       = (const float*)d_in[4];
  const float* bn_b       = (const float*)d_in[5];
  const float* in_proj_w  = (const float*)d_in[6];
  const float* in_proj_b  = (const float*)d_in[7];
  const float* dist_scale = (const float*)d_in[8];
  const float* lin1_w     = (const float*)d_in[9];
  const float* lin1_b     = (const float*)d_in[10];
  const float* lin2_w     = (const float*)d_in[11];
  const float* lin2_b     = (const float*)d_in[12];
  const float* n1_g       = (const float*)d_in[13];
  const float* n1_b       = (const float*)d_in[14];
  const float* n2_g       = (const float*)d_in[15];
  const float* n2_b       = (const float*)d_in[16];

  float* x = (float*)d_out;                      // fp32 activations [N,E]

  // workspace layout (≈88 MB)
  float* stats = (float*)d_ws;                   // B*H*S*2
  float* den   = stats + 131072;                 // B*S
  float* bnst  = den + 8192;                     // 2*E
  float* aout  = bnst + 1024;                    // N*E fp32
  float* x0    = aout;                           // alias (pre-loop only)
  bf16* db_b = (bf16*)(aout + (size_t)Nz * Ez);  // B*S*S
  bf16* Rqk  = db_b + (size_t)Bz * Sz * Sz;      // union region: qk+aw | ff1
  bf16* qk   = Rqk;                              // N*1024
  bf16* aw   = Rqk + (size_t)Nz * 1024;          // B*S*S
  bf16* ff1  = Rqk;                              // N*FF (aliases qk+aw, disjoint lifetime)
  bf16* xb   = Rqk + (size_t)Nz * FFz;           // N*E
  bf16* xT   = xb + (size_t)Nz * Ez;             // B*E*S
  bf16* srcb = xT + (size_t)Bz * Ez * Sz;        // N*IN
  bf16* wpr  = srcb + (size_t)Nz * INz;          // E*IN
  bf16* wqk  = wpr + Ez * INz;                   // 1024*E (q,k rows only)
  bf16* wl1  = wqk + 1024 * Ez;                  // FF*E
  bf16* wl2  = wl1 + FFz * Ez;                   // E*FF

  // weight / input casts
  cast_f2b<<<(Nz * INz) / 256, 256, 0, stream>>>(src, srcb, Nz * INz);
  cast_f2b<<<(Ez * INz + 255) / 256, 256, 0, stream>>>(proj_w, wpr, Ez * INz);
  cast_f2b<<<(1024 * Ez) / 256, 256, 0, stream>>>(in_proj_w, wqk, 1024 * Ez);
  cast_f2b<<<(FFz * Ez) / 256, 256, 0, stream>>>(lin1_w, wl1, FFz * Ez);
  cast_f2b<<<(Ez * FFz) / 256, 256, 0, stream>>>(lin2_w, wl2, Ez * FFz);

  // input projection -> x0 fp32
  gemm_bt<<<dim3(Ez / 128, Nz / 128, 1), 256, 0, stream>>>(
      srcb, wpr, proj_b, x0, nullptr, nullptr, Nz, Ez, INz, 0, 0, 0, 0);
  bn_stats<<<Ez, 256, 0, stream>>>(x0, bnst);
  bn_apply_pe<<<(Nz * Ez) / 256, 256, 0, stream>>>(x0, bnst, bn_g, bn_b, x, xb);
  dist_bias_k<<<Bz * Sz, 256, 0, stream>>>(distances, dist_scale, db_b);

  for (int l = 0; l < Lz; ++l) {
    // transpose layer-entry x (values for PV)
    transpose_xb<<<dim3(Sz / 32, Ez / 32, Bz), 256, 0, stream>>>(xb, xT);
    // q,k projection -> qk bf16 [N,1024]
    gemm_bt<<<dim3(1024 / 128, Nz / 128, 1), 256, 0, stream>>>(
        xb, wqk, in_proj_b, nullptr, qk, nullptr, Nz, 1024, Ez, 0, 0, 0, 0);
    attn_stats2<<<dim3(Sz / 64, Hz, Bz), 256, 0, stream>>>(qk, stats);
    scores_bias<<<dim3(Sz / 32, Sz / 32, Bz), 256, 0, stream>>>(qk, db_b, stats, aw);
    rowsum<<<Bz * Sz, 256, 0, stream>>>(aw, den);
    // PV: batched aw[b] @ x[b]  (values = layer-entry x), renorm by den
    gemm_bt<<<dim3(Ez / 128, Sz / 128, Bz), 256, 0, stream>>>(
        aw, xT, nullptr, aout, nullptr, den,
        Sz, Ez, Sz, (long)Sz * Sz, (long)Ez * Sz, (long)Sz * Ez, 0);
    add_ln<<<Nz, 256, 0, stream>>>(x, aout, n1_g, n1_b, x, xb);
    // FF
    gemm_bt<<<dim3(FFz / 128, Nz / 128, 1), 256, 0, stream>>>(
        xb, wl1, lin1_b, nullptr, ff1, nullptr, Nz, FFz, Ez, 0, 0, 0, 1);
    gemm_bt<<<dim3(Ez / 128, Nz / 128, 1), 256, 0, stream>>>(
        ff1, wl2, lin2_b, aout, nullptr, nullptr, Nz, Ez, FFz, 0, 0, 0, 0);
    add_ln<<<Nz, 256, 0, stream>>>(x, aout, n2_g, n2_b, x, xb);
  }
}